// Round 7
// baseline (434.306 us; speedup 1.0000x reference)
//
#include <hip/hip_runtime.h>
#include <hip/hip_bf16.h>
#include <math.h>

#define NUM_GRAPHS 1024
#define NBLK 512          // edge-blocks in counting-sort passes

typedef __attribute__((ext_vector_type(8))) short bf16x8;
typedef __attribute__((ext_vector_type(4))) float f32x4;

static __device__ __forceinline__ unsigned short f2bf(float f) {
    union { float f; unsigned u; } v; v.f = f;
    unsigned r = v.u + 0x7fffu + ((v.u >> 16) & 1u);   // round-to-nearest-even
    return (unsigned short)(r >> 16);
}
static __device__ __forceinline__ float bf_lo(unsigned u) { return __uint_as_float(u << 16); }
static __device__ __forceinline__ float bf_hi(unsigned u) { return __uint_as_float(u & 0xffff0000u); }

// exclusive scan of tot[0..nbuck) into LDS bb[0..nbuck] (bb[nbuck]=grand total).
static __device__ void scan_tot(const int* __restrict__ tot, int nbuck,
                                int* bb, int* tmp) {
    const int t = threadIdx.x;
    int v[4];
    int lsum = 0;
    #pragma unroll
    for (int j = 0; j < 4; ++j) {
        int idx = 4 * t + j;
        v[j] = (idx < nbuck) ? tot[idx] : 0;
        lsum += v[j];
    }
    tmp[t] = lsum;
    __syncthreads();
    for (int off = 1; off < 256; off <<= 1) {
        int a = (t >= off) ? tmp[t - off] : 0;
        __syncthreads();
        tmp[t] += a;
        __syncthreads();
    }
    int run = tmp[t] - lsum;
    #pragma unroll
    for (int j = 0; j < 4; ++j) {
        int idx = 4 * t + j;
        if (idx < nbuck) bb[idx] = run;
        run += v[j];
    }
    if (t == 255) bb[nbuck] = tmp[255];
    __syncthreads();
}

// ---------------- P1 (+ x->bf16 slab-major + zero G) ----------------
// Slab layout: Hs[slice][node][32B], slice = feature/16, 8 slices.
__global__ void k_pre(const int* __restrict__ eiDst, int E, int epb, int nbuck,
                      int* __restrict__ cnt,
                      const float* __restrict__ x, int N, unsigned* __restrict__ xb,
                      float* __restrict__ G) {
    if ((int)blockIdx.x < NBLK) {
        __shared__ int hist[1024];
        const int t = threadIdx.x;
        for (int i = t; i < 1024; i += 256) hist[i] = 0;
        __syncthreads();
        const int kb = blockIdx.x;
        const int e0 = kb * epb;
        const int e1 = min(E, e0 + epb);
        for (int e = e0 + t; e < e1; e += 256) atomicAdd(&hist[eiDst[e] >> 7], 1);
        __syncthreads();
        for (int b = t; b < nbuck; b += 256) cnt[(size_t)b * NBLK + kb] = hist[b];
    } else if ((int)blockIdx.x < NBLK + 2048) {
        const int n4 = N * 32;
        int i = (blockIdx.x - NBLK) * 256 + threadIdx.x;
        const int stride = 2048 * 256;
        const float4* x4 = (const float4*)x;
        for (; i < n4; i += stride) {
            float4 v = x4[i];
            unsigned lo = (unsigned)f2bf(v.x) | ((unsigned)f2bf(v.y) << 16);
            unsigned hi = (unsigned)f2bf(v.z) | ((unsigned)f2bf(v.w) << 16);
            int n = i >> 5, fq = i & 31;
            int s = fq >> 2;
            ((uint2*)xb)[(size_t)(s * N + n) * 4 + (fq & 3)] = make_uint2(lo, hi);
        }
    } else {
        int i = (blockIdx.x - NBLK - 2048) * 256 + threadIdx.x;
        float4* G4 = (float4*)G;
        for (; i < NUM_GRAPHS * 32; i += 64 * 256)
            G4[i] = make_float4(0.f, 0.f, 0.f, 0.f);
    }
}

// ---------------- column scan, block-per-bucket ----------------
__global__ void k_colscan(const int* __restrict__ cnt, int nbuck,
                          int* __restrict__ pref, int* __restrict__ tot) {
    __shared__ int s[512];
    const int b = blockIdx.x;
    if (b >= nbuck) return;
    const int t = threadIdx.x;
    const int* c = cnt + (size_t)b * NBLK;
    int v0 = c[t], v1 = c[t + 256];
    s[t] = v0; s[t + 256] = v1;
    __syncthreads();
    for (int off = 1; off < 512; off <<= 1) {
        int a = (t >= off) ? s[t - off] : 0;
        int bsec = s[t + 256 - off];
        __syncthreads();
        s[t] += a;
        s[t + 256] += bsec;
        __syncthreads();
    }
    pref[(size_t)b * NBLK + t] = s[t] - v0;
    pref[(size_t)b * NBLK + t + 256] = s[t + 256] - v1;
    if (t == 255) tot[b] = s[511];
}

// ---------------- P2: scatter edges into bucket-sorted ebuf (packed d7|src) ----------------
__global__ void k_scatter(const int* __restrict__ eiSrc, const int* __restrict__ eiDst,
                          int E, int epb, const int* __restrict__ pref,
                          const int* __restrict__ tot, int nbuck,
                          unsigned* __restrict__ ebuf) {
    __shared__ int bb[1025];
    __shared__ int tmp[256];
    __shared__ int cur[1024];
    const int t = threadIdx.x;
    const int kb = blockIdx.x;
    scan_tot(tot, nbuck, bb, tmp);
    for (int b = t; b < nbuck; b += 256) cur[b] = bb[b] + pref[(size_t)b * NBLK + kb];
    __syncthreads();
    const int e0 = kb * epb;
    const int e1 = min(E, e0 + epb);
    for (int e = e0 + t; e < e1; e += 256) {
        int d = eiDst[e];
        int s = eiSrc[e];
        int pos = atomicAdd(&cur[d >> 7], 1);
        ebuf[pos] = (unsigned)s | ((unsigned)(d & 127) << 25);
    }
}

// ---------------- P3: per-bucket fine sort -> rp + srcs; extra blocks do weight prep ----------------
__global__ void k_bucket(const unsigned* __restrict__ ebuf, const int* __restrict__ tot,
                         int nbuck, int N, int* __restrict__ rp, int* __restrict__ srcs,
                         const float* __restrict__ W0, const float* __restrict__ W1,
                         const float* __restrict__ W2, const float* __restrict__ W3,
                         unsigned short* __restrict__ wt) {
    if ((int)blockIdx.x >= nbuck) {
        int lb = blockIdx.x - nbuck;                // 0..255
        int b4 = lb >> 6;                           // 0..3
        const float* W = (b4 == 0) ? W0 : (b4 == 1) ? W1 : (b4 == 2) ? W2 : W3;
        int idx = (lb & 63) * 256 + threadIdx.x;    // 0..16383
        int k = idx >> 7, n = idx & 127;
        wt[b4 * 16384 + n * 128 + k] = f2bf(W[idx]);
        return;
    }
    __shared__ int bb[1025];
    __shared__ int tmp[256];
    __shared__ int h[128];
    __shared__ int cur[128];
    const int t = threadIdx.x;
    const int b = blockIdx.x;
    scan_tot(tot, nbuck, bb, tmp);
    const int base = bb[b];
    const int cntb = bb[b + 1] - base;
    if (t < 128) h[t] = 0;
    __syncthreads();
    for (int i = t; i < cntb; i += 256) atomicAdd(&h[ebuf[base + i] >> 25], 1);
    __syncthreads();
    int c0 = (t < 128) ? h[t] : 0;
    for (int off = 1; off < 128; off <<= 1) {
        int a = (t >= off && t < 128) ? h[t - off] : 0;
        __syncthreads();
        if (t < 128) h[t] += a;
        __syncthreads();
    }
    if (t < 128) {
        int excl = h[t] - c0;
        cur[t] = excl;
        int d = (b << 7) + t;
        if (d < N) rp[d] = base + excl;
        if (d == N) rp[N] = base + excl;
    }
    __syncthreads();
    for (int i = t; i < cntb; i += 256) {
        unsigned pck = ebuf[base + i];
        int pos = atomicAdd(&cur[pck >> 25], 1);
        srcs[base + pos] = (int)(pck & 0x01FFFFFFu);
    }
}

// ---------------- XCD-slab aggregation ----------------
// Input Hs slab-major (8 slices x 32B); output row-major (for MLP staging).
// Block handles slice = blockIdx&7 -> round-robin XCD dispatch keeps each
// XCD's 3.2 MB slab L2-resident. 2 lanes per node (uint4 = 8 features each),
// 32 nodes per wave. No cross-lane reduction needed.
__device__ __forceinline__ void acc8(float* a, uint4 v) {
    a[0] += bf_lo(v.x); a[1] += bf_hi(v.x);
    a[2] += bf_lo(v.y); a[3] += bf_hi(v.y);
    a[4] += bf_lo(v.z); a[5] += bf_hi(v.z);
    a[6] += bf_lo(v.w); a[7] += bf_hi(v.w);
}

__global__ __launch_bounds__(256, 8)
void k_aggs(const uint4* __restrict__ Hs, const int* __restrict__ rp,
            const int* __restrict__ srcs, int N, uint4* __restrict__ out) {
    const int slice = blockIdx.x & 7;
    const int chunk = blockIdx.x >> 3;
    const int tid = threadIdx.x;
    const int lane = tid & 63;
    const int w = tid >> 6;
    const int pair = lane >> 1, half = lane & 1;
    const int n = chunk * 128 + w * 32 + pair;
    if (n >= N) return;
    const size_t sbase = (size_t)slice * N;
    uint4 s0 = Hs[(sbase + n) * 2 + half];
    float a[8];
    a[0] = bf_lo(s0.x); a[1] = bf_hi(s0.x);
    a[2] = bf_lo(s0.y); a[3] = bf_hi(s0.y);
    a[4] = bf_lo(s0.z); a[5] = bf_hi(s0.z);
    a[6] = bf_lo(s0.w); a[7] = bf_hi(s0.w);
    int j = rp[n], e = rp[n + 1];
    while (j + 4 <= e) {
        int i0 = srcs[j], i1 = srcs[j + 1], i2 = srcs[j + 2], i3 = srcs[j + 3];
        uint4 v0 = Hs[(sbase + i0) * 2 + half];
        uint4 v1 = Hs[(sbase + i1) * 2 + half];
        uint4 v2 = Hs[(sbase + i2) * 2 + half];
        uint4 v3 = Hs[(sbase + i3) * 2 + half];
        acc8(a, v0); acc8(a, v1); acc8(a, v2); acc8(a, v3);
        j += 4;
    }
    while (j < e) {
        uint4 v = Hs[(sbase + srcs[j]) * 2 + half];
        acc8(a, v);
        ++j;
    }
    uint4 o;
    o.x = (unsigned)f2bf(a[0]) | ((unsigned)f2bf(a[1]) << 16);
    o.y = (unsigned)f2bf(a[2]) | ((unsigned)f2bf(a[3]) << 16);
    o.z = (unsigned)f2bf(a[4]) | ((unsigned)f2bf(a[5]) << 16);
    o.w = (unsigned)f2bf(a[6]) | ((unsigned)f2bf(a[7]) << 16);
    out[(size_t)n * 16 + slice * 2 + half] = o;
}

// ---------------- fused 2-layer MLP ----------------
// !POOL: writes Y in SLAB-major bf16 (consumed by next k_aggs).
// POOL:  pools relu(out) into G (fp32 atomics), no Y write.
__device__ __forceinline__ int swz_base(int row, int chunk) {
    return row * 128 + ((chunk ^ (row & 7)) << 3);
}

template <bool POOL>
__global__ __launch_bounds__(256, 2)
void k_mlp(const unsigned short* __restrict__ U, int N,
           const unsigned short* __restrict__ WaT, const float* __restrict__ ba,
           const unsigned short* __restrict__ WbT, const float* __restrict__ bb,
           unsigned short* __restrict__ Y,
           const int* __restrict__ batch, float* __restrict__ G) {
    __shared__ unsigned short lA[128 * 128];
    __shared__ unsigned short lW[128 * 128];
    __shared__ int bs[128];

    const int tid = threadIdx.x;
    const int lane = tid & 63;
    const int w = tid >> 6;
    const int wr = (w >> 1) * 64;
    const int wc = (w & 1) * 64;
    const int r0 = blockIdx.x * 128;

    {
        const uint4* U4 = (const uint4*)U;
        #pragma unroll
        for (int i = 0; i < 8; ++i) {
            int c = tid + 256 * i;
            int row = c >> 4, q = c & 15;
            uint4 v = (r0 + row < N) ? U4[(size_t)(r0 + row) * 16 + q]
                                     : make_uint4(0u, 0u, 0u, 0u);
            *(uint4*)&lA[swz_base(row, q)] = v;
        }
    }
    {
        const uint4* Wsrc = (const uint4*)WaT;
        #pragma unroll
        for (int i = 0; i < 8; ++i) {
            int c = tid + 256 * i;
            int row = c >> 4, q = c & 15;
            *(uint4*)&lW[swz_base(row, q)] = Wsrc[c];
        }
    }
    __syncthreads();

    const int am = lane & 15;
    const int kq = (lane >> 4) * 8;

    f32x4 acc[4][4];
    #pragma unroll
    for (int i = 0; i < 4; ++i)
        #pragma unroll
        for (int j = 0; j < 4; ++j) acc[i][j] = (f32x4){0.f, 0.f, 0.f, 0.f};

    #pragma unroll
    for (int ks = 0; ks < 4; ++ks) {
        int k0 = ks * 32 + kq;
        bf16x8 af[4], bq[4];
        #pragma unroll
        for (int i = 0; i < 4; ++i)
            af[i] = *(const bf16x8*)&lA[swz_base(wr + i * 16 + am, k0 >> 3)];
        #pragma unroll
        for (int j = 0; j < 4; ++j)
            bq[j] = *(const bf16x8*)&lW[swz_base(wc + j * 16 + am, k0 >> 3)];
        #pragma unroll
        for (int i = 0; i < 4; ++i)
            #pragma unroll
            for (int j = 0; j < 4; ++j)
                acc[i][j] = __builtin_amdgcn_mfma_f32_16x16x32_bf16(af[i], bq[j], acc[i][j], 0, 0, 0);
    }
    __syncthreads();

    #pragma unroll
    for (int j = 0; j < 4; ++j) {
        int col = wc + j * 16 + am;
        float bias = ba[col];
        #pragma unroll
        for (int i = 0; i < 4; ++i) {
            int rowb = wr + i * 16 + (lane >> 4) * 4;
            #pragma unroll
            for (int r = 0; r < 4; ++r) {
                float t = acc[i][j][r] + bias;
                t = t > 0.f ? t : 0.f;
                int row = rowb + r;
                lA[swz_base(row, col >> 3) + (col & 7)] = f2bf(t);
            }
        }
    }
    {
        const uint4* Wsrc = (const uint4*)WbT;
        #pragma unroll
        for (int i = 0; i < 8; ++i) {
            int c = tid + 256 * i;
            int row = c >> 4, q = c & 15;
            *(uint4*)&lW[swz_base(row, q)] = Wsrc[c];
        }
    }
    __syncthreads();

    #pragma unroll
    for (int i = 0; i < 4; ++i)
        #pragma unroll
        for (int j = 0; j < 4; ++j) acc[i][j] = (f32x4){0.f, 0.f, 0.f, 0.f};

    #pragma unroll
    for (int ks = 0; ks < 4; ++ks) {
        int k0 = ks * 32 + kq;
        bf16x8 af[4], bq[4];
        #pragma unroll
        for (int i = 0; i < 4; ++i)
            af[i] = *(const bf16x8*)&lA[swz_base(wr + i * 16 + am, k0 >> 3)];
        #pragma unroll
        for (int j = 0; j < 4; ++j)
            bq[j] = *(const bf16x8*)&lW[swz_base(wc + j * 16 + am, k0 >> 3)];
        #pragma unroll
        for (int i = 0; i < 4; ++i)
            #pragma unroll
            for (int j = 0; j < 4; ++j)
                acc[i][j] = __builtin_amdgcn_mfma_f32_16x16x32_bf16(af[i], bq[j], acc[i][j], 0, 0, 0);
    }

    if (!POOL) {
        // epilogue: Y (slab-major) = relu(acc + bb)
        #pragma unroll
        for (int j = 0; j < 4; ++j) {
            int col = wc + j * 16 + am;
            float bias = bb[col];
            int s = col >> 4;
            int uoff = (col & 15) >> 1;
            int hh = col & 1;
            #pragma unroll
            for (int i = 0; i < 4; ++i) {
                int rowb = wr + i * 16 + (lane >> 4) * 4;
                #pragma unroll
                for (int r = 0; r < 4; ++r) {
                    int row = r0 + rowb + r;
                    if (row < N) {
                        float t = acc[i][j][r] + bias;
                        t = t > 0.f ? t : 0.f;
                        Y[((size_t)(s * N + row) * 8 + uoff) * 2 + hh] = f2bf(t);
                    }
                }
            }
        }
    } else {
        __syncthreads();
        #pragma unroll
        for (int j = 0; j < 4; ++j) {
            int col = wc + j * 16 + am;
            float bias = bb[col];
            #pragma unroll
            for (int i = 0; i < 4; ++i) {
                int rowb = wr + i * 16 + (lane >> 4) * 4;
                #pragma unroll
                for (int r = 0; r < 4; ++r) {
                    float t = acc[i][j][r] + bias;
                    t = t > 0.f ? t : 0.f;
                    int row = rowb + r;
                    lA[swz_base(row, col >> 3) + (col & 7)] = f2bf(t);
                }
            }
        }
        if (tid < 128) bs[tid] = (r0 + tid < N) ? batch[r0 + tid] : -1;
        __syncthreads();
        const int col = tid & 127;
        const int half = tid >> 7;
        const int rbeg = half * 64, rend = rbeg + 64;
        float pacc = 0.f;
        int cur = bs[rbeg];
        for (int row = rbeg; row < rend; ++row) {
            int b = bs[row];
            if (b != cur) {
                if (cur >= 0) atomicAdd(&G[(size_t)cur * 128 + col], pacc);
                pacc = 0.f;
                cur = b;
            }
            unsigned short u = lA[swz_base(row, col >> 3) + (col & 7)];
            pacc += __uint_as_float((unsigned)u << 16);
        }
        if (cur >= 0) atomicAdd(&G[(size_t)cur * 128 + col], pacc);
    }
}

// ---------------- head ----------------
__global__ void k_head(const float* __restrict__ G,
                       const float* __restrict__ Wl1, const float* __restrict__ bl1,
                       const float* __restrict__ Wl2, const float* __restrict__ bl2,
                       int C, float* __restrict__ out) {
    __shared__ float sg[128];
    __shared__ float sh[128];
    __shared__ float sl[16];
    int row = blockIdx.x;
    int t = threadIdx.x;
    sg[t] = G[(size_t)row * 128 + t];
    __syncthreads();
    float a = bl1[t];
    for (int k = 0; k < 128; ++k) a += sg[k] * Wl1[k * 128 + t];
    sh[t] = a > 0.f ? a : 0.f;
    __syncthreads();
    if (t < C) {
        float l = bl2[t];
        for (int k = 0; k < 128; ++k) l += sh[k] * Wl2[k * C + t];
        sl[t] = l;
    }
    __syncthreads();
    if (t < C) {
        float m = -1e30f;
        for (int j = 0; j < C; ++j) m = fmaxf(m, sl[j]);
        float s = 0.f;
        for (int j = 0; j < C; ++j) s += __expf(sl[j] - m);
        out[(size_t)row * C + t] = sl[t] - m - __logf(s);
    }
}

extern "C" void kernel_launch(void* const* d_in, const int* in_sizes, int n_in,
                              void* d_out, int out_size, void* d_ws, size_t ws_size,
                              hipStream_t stream) {
    const float* x    = (const float*)d_in[0];
    const int*   ei   = (const int*)d_in[1];     // [2][E]
    const int*   batch= (const int*)d_in[2];
    const float* W1a  = (const float*)d_in[3];
    const float* b1a  = (const float*)d_in[4];
    const float* W1b  = (const float*)d_in[5];
    const float* b1b  = (const float*)d_in[6];
    const float* W2a  = (const float*)d_in[7];
    const float* b2a  = (const float*)d_in[8];
    const float* W2b  = (const float*)d_in[9];
    const float* b2b  = (const float*)d_in[10];
    const float* Wl1  = (const float*)d_in[11];
    const float* bl1  = (const float*)d_in[12];
    const float* Wl2  = (const float*)d_in[13];
    const float* bl2  = (const float*)d_in[14];
    float* out = (float*)d_out;

    const int N = in_sizes[2];
    const int E = in_sizes[1] / 2;
    const int C = in_sizes[13] / 128;

    const int nbuck = (N >> 7) + 1;
    const int epb = (E + NBLK - 1) / NBLK;

    char* p = (char*)d_ws;
    auto alloc = [&](size_t bytes) {
        char* r = p;
        p += (bytes + 255) & ~(size_t)255;
        return r;
    };
    unsigned* xb   = (unsigned*)alloc((size_t)N * 64 * 4);     // x bf16, slab-major
    unsigned* hA   = (unsigned*)alloc((size_t)N * 64 * 4);     // agg out, row-major
    unsigned* hB   = (unsigned*)alloc((size_t)N * 64 * 4);     // conv1 out, slab-major
    float* g       = (float*)alloc((size_t)NUM_GRAPHS * 128 * 4);
    int* rp        = (int*)alloc((size_t)(N + 1) * 4);
    int* srcs      = (int*)alloc((size_t)E * 4);
    unsigned* ebuf = (unsigned*)alloc((size_t)E * 4);
    int* cnt       = (int*)alloc((size_t)nbuck * NBLK * 4);
    int* pref      = (int*)alloc((size_t)nbuck * NBLK * 4);
    int* tot       = (int*)alloc((size_t)1024 * 4);
    unsigned short* wt = (unsigned short*)alloc((size_t)4 * 16384 * 2);
    (void)ws_size; (void)n_in; (void)out_size;

    // CSR build (counting sort) + x->bf16 slab + zero G
    k_pre<<<NBLK + 2048 + 64, 256, 0, stream>>>(ei + E, E, epb, nbuck, cnt, x, N, xb, g);
    k_colscan<<<nbuck, 256, 0, stream>>>(cnt, nbuck, pref, tot);
    k_scatter<<<NBLK, 256, 0, stream>>>(ei, ei + E, E, epb, pref, tot, nbuck, ebuf);
    k_bucket<<<nbuck + 256, 256, 0, stream>>>(ebuf, tot, nbuck, N, rp, srcs,
                                              W1a, W1b, W2a, W2b, wt);

    const int mb = (N + 127) / 128;
    const int ab = ((N + 127) / 128) * 8;    // (node-chunk of 128) x 8 slices

    // conv1
    k_aggs<<<ab, 256, 0, stream>>>((const uint4*)xb, rp, srcs, N, (uint4*)hA);
    k_mlp<false><<<mb, 256, 0, stream>>>((const unsigned short*)hA, N, wt, b1a,
                                         wt + 16384, b1b, (unsigned short*)hB,
                                         nullptr, nullptr);
    // conv2 (+ fused global_add_pool)
    k_aggs<<<ab, 256, 0, stream>>>((const uint4*)hB, rp, srcs, N, (uint4*)hA);
    k_mlp<true><<<mb, 256, 0, stream>>>((const unsigned short*)hA, N, wt + 2 * 16384, b2a,
                                        wt + 3 * 16384, b2b, nullptr,
                                        batch, g);
    // head
    k_head<<<NUM_GRAPHS, 128, 0, stream>>>(g, Wl1, bl1, Wl2, bl2, C, out);
}

// Round 8
// 368.029 us; speedup vs baseline: 1.1801x; 1.1801x over previous
//
#include <hip/hip_runtime.h>
#include <hip/hip_bf16.h>
#include <math.h>

#define NUM_GRAPHS 1024
#define SBLK 256          // sort blocks in fused CSR kernel
#define CAP 4096          // per-bucket ebuf capacity (mean 2046, 45 sigma)

typedef __attribute__((ext_vector_type(8))) short bf16x8;
typedef __attribute__((ext_vector_type(4))) float f32x4;

static __device__ __forceinline__ unsigned short f2bf(float f) {
    union { float f; unsigned u; } v; v.f = f;
    unsigned r = v.u + 0x7fffu + ((v.u >> 16) & 1u);   // round-to-nearest-even
    return (unsigned short)(r >> 16);
}
static __device__ __forceinline__ float bf_lo(unsigned u) { return __uint_as_float(u << 16); }
static __device__ __forceinline__ float bf_hi(unsigned u) { return __uint_as_float(u & 0xffff0000u); }

// exclusive scan of min(tot[i],CAP) into LDS bb[0..nbuck]; 256 threads, nbuck<=1024
static __device__ void scan_tot(const int* __restrict__ tot, int nbuck,
                                int* bb, int* tmp) {
    const int t = threadIdx.x;
    int v[4];
    int lsum = 0;
    #pragma unroll
    for (int j = 0; j < 4; ++j) {
        int idx = 4 * t + j;
        v[j] = (idx < nbuck) ? min(tot[idx], CAP) : 0;
        lsum += v[j];
    }
    tmp[t] = lsum;
    __syncthreads();
    for (int off = 1; off < 256; off <<= 1) {
        int a = (t >= off) ? tmp[t - off] : 0;
        __syncthreads();
        tmp[t] += a;
        __syncthreads();
    }
    int run = tmp[t] - lsum;
    #pragma unroll
    for (int j = 0; j < 4; ++j) {
        int idx = 4 * t + j;
        if (idx < nbuck) bb[idx] = run;
        run += v[j];
    }
    if (t == 255) bb[nbuck] = tmp[255];
    __syncthreads();
}

// ---------------- fused CSR pass 1: hist + chunk-reserve + scatter ----------------
// Also: x->bf16 (row-major), zero G, weight prep — as extra block ranges.
// gcur[] must be zeroed before this kernel (hipMemsetAsync).
__global__ void k_sort(const int* __restrict__ eiSrc, const int* __restrict__ eiDst,
                       int E, int epb, int nbuck,
                       int* __restrict__ gcur, unsigned* __restrict__ ebuf,
                       const float* __restrict__ x, int N, unsigned* __restrict__ xb,
                       float* __restrict__ G,
                       const float* __restrict__ W0, const float* __restrict__ W1,
                       const float* __restrict__ W2, const float* __restrict__ W3,
                       unsigned short* __restrict__ wt) {
    if ((int)blockIdx.x < SBLK) {
        __shared__ int hist[1024];
        __shared__ int cur[1024];
        const int t = threadIdx.x;
        for (int i = t; i < 1024; i += 256) hist[i] = 0;
        __syncthreads();
        const int e0 = blockIdx.x * epb;
        const int e1 = min(E, e0 + epb);
        for (int e = e0 + t; e < e1; e += 256) atomicAdd(&hist[eiDst[e] >> 7], 1);
        __syncthreads();
        for (int b = t; b < nbuck; b += 256) {
            int c = hist[b];
            cur[b] = b * CAP + (c > 0 ? atomicAdd(&gcur[b], c) : 0);
        }
        __syncthreads();
        for (int e = e0 + t; e < e1; e += 256) {
            int d = eiDst[e];
            int s = eiSrc[e];
            int b = d >> 7;
            int pos = atomicAdd(&cur[b], 1);
            if (pos < (b + 1) * CAP)   // overflow guard (45-sigma event)
                ebuf[pos] = (unsigned)s | ((unsigned)(d & 127) << 25);
        }
    } else if ((int)blockIdx.x < SBLK + 2048) {
        const int n4 = N * 32;
        int i = (blockIdx.x - SBLK) * 256 + threadIdx.x;
        const int stride = 2048 * 256;
        const float4* x4 = (const float4*)x;
        for (; i < n4; i += stride) {
            float4 v = x4[i];
            unsigned lo = (unsigned)f2bf(v.x) | ((unsigned)f2bf(v.y) << 16);
            unsigned hi = (unsigned)f2bf(v.z) | ((unsigned)f2bf(v.w) << 16);
            ((uint2*)xb)[i] = make_uint2(lo, hi);
        }
    } else if ((int)blockIdx.x < SBLK + 2048 + 64) {
        int i = (blockIdx.x - SBLK - 2048) * 256 + threadIdx.x;
        float4* G4 = (float4*)G;
        for (; i < NUM_GRAPHS * 32; i += 64 * 256)
            G4[i] = make_float4(0.f, 0.f, 0.f, 0.f);
    } else {
        int lb = blockIdx.x - SBLK - 2048 - 64;     // 0..255
        int b4 = lb >> 6;                           // 0..3
        const float* W = (b4 == 0) ? W0 : (b4 == 1) ? W1 : (b4 == 2) ? W2 : W3;
        int idx = (lb & 63) * 256 + threadIdx.x;    // 0..16383
        int k = idx >> 7, n = idx & 127;
        wt[b4 * 16384 + n * 128 + k] = f2bf(W[idx]);
    }
}

// ---------------- CSR pass 2: per-bucket fine sort -> rp + srcs ----------------
__global__ void k_bucket(const unsigned* __restrict__ ebuf, const int* __restrict__ gcur,
                         int nbuck, int N, int* __restrict__ rp, int* __restrict__ srcs) {
    __shared__ int bb[1025];
    __shared__ int tmp[256];
    __shared__ int h[128];
    __shared__ int cur[128];
    const int t = threadIdx.x;
    const int b = blockIdx.x;
    scan_tot(gcur, nbuck, bb, tmp);
    const int base = bb[b];
    const int cntb = bb[b + 1] - base;
    const unsigned* eb = ebuf + (size_t)b * CAP;
    if (t < 128) h[t] = 0;
    __syncthreads();
    for (int i = t; i < cntb; i += 256) atomicAdd(&h[eb[i] >> 25], 1);
    __syncthreads();
    int c0 = (t < 128) ? h[t] : 0;
    for (int off = 1; off < 128; off <<= 1) {
        int a = (t >= off && t < 128) ? h[t - off] : 0;
        __syncthreads();
        if (t < 128) h[t] += a;
        __syncthreads();
    }
    if (t < 128) {
        int excl = h[t] - c0;
        cur[t] = excl;
        int d = (b << 7) + t;
        if (d < N) rp[d] = base + excl;
        if (d == N) rp[N] = base + excl;
    }
    __syncthreads();
    for (int i = t; i < cntb; i += 256) {
        unsigned pck = eb[i];
        int pos = atomicAdd(&cur[pck >> 25], 1);
        srcs[base + pos] = (int)(pck & 0x01FFFFFFu);
    }
}

// ---------------- quarter-wave aggregation (bf16 in/out, fp32 accumulate) ----------------
// 16 lanes per node, lane holds uint4 = 8 bf16 features; one load instruction
// moves up to 4 rows (1 KB) for 4 dst nodes. [R4: VMEM-issue-bound fix]
__device__ __forceinline__ void acc8(float* a, uint4 v) {
    a[0] += bf_lo(v.x); a[1] += bf_hi(v.x);
    a[2] += bf_lo(v.y); a[3] += bf_hi(v.y);
    a[4] += bf_lo(v.z); a[5] += bf_hi(v.z);
    a[6] += bf_lo(v.w); a[7] += bf_hi(v.w);
}

__global__ __launch_bounds__(256, 8)
void k_aggq(const uint4* __restrict__ H4, const int* __restrict__ rp,
            const int* __restrict__ srcs, int N, uint4* __restrict__ out) {
    int gw = (blockIdx.x * blockDim.x + threadIdx.x) >> 6;
    int lane = threadIdx.x & 63;
    int q = lane >> 4, ql = lane & 15;
    int n = gw * 4 + q;
    if (gw * 4 >= N) return;
    bool act = (n < N);
    int nc = act ? n : 0;
    uint4 s0 = H4[(size_t)nc * 16 + ql];
    float a[8];
    a[0] = bf_lo(s0.x); a[1] = bf_hi(s0.x);
    a[2] = bf_lo(s0.y); a[3] = bf_hi(s0.y);
    a[4] = bf_lo(s0.z); a[5] = bf_hi(s0.z);
    a[6] = bf_lo(s0.w); a[7] = bf_hi(s0.w);
    int j = act ? rp[nc] : 0;
    int e = act ? rp[nc + 1] : 0;
    while (j + 4 <= e) {
        int i0 = srcs[j], i1 = srcs[j + 1], i2 = srcs[j + 2], i3 = srcs[j + 3];
        uint4 v0 = H4[(size_t)i0 * 16 + ql];
        uint4 v1 = H4[(size_t)i1 * 16 + ql];
        uint4 v2 = H4[(size_t)i2 * 16 + ql];
        uint4 v3 = H4[(size_t)i3 * 16 + ql];
        acc8(a, v0); acc8(a, v1); acc8(a, v2); acc8(a, v3);
        j += 4;
    }
    while (j < e) {
        uint4 v = H4[(size_t)srcs[j] * 16 + ql];
        acc8(a, v);
        ++j;
    }
    if (act) {
        uint4 o;
        o.x = (unsigned)f2bf(a[0]) | ((unsigned)f2bf(a[1]) << 16);
        o.y = (unsigned)f2bf(a[2]) | ((unsigned)f2bf(a[3]) << 16);
        o.z = (unsigned)f2bf(a[4]) | ((unsigned)f2bf(a[5]) << 16);
        o.w = (unsigned)f2bf(a[6]) | ((unsigned)f2bf(a[7]) << 16);
        out[(size_t)n * 16 + ql] = o;
    }
}

// ---------------- fused 2-layer MLP; POOL variant pools into G ----------------
__device__ __forceinline__ int swz_base(int row, int chunk) {
    return row * 128 + ((chunk ^ (row & 7)) << 3);
}

template <bool POOL>
__global__ __launch_bounds__(256, 2)
void k_mlp(const unsigned short* __restrict__ U, int N,
           const unsigned short* __restrict__ WaT, const float* __restrict__ ba,
           const unsigned short* __restrict__ WbT, const float* __restrict__ bb,
           unsigned short* __restrict__ Y,
           const int* __restrict__ batch, float* __restrict__ G) {
    __shared__ unsigned short lA[128 * 128];
    __shared__ unsigned short lW[128 * 128];
    __shared__ int bs[128];

    const int tid = threadIdx.x;
    const int lane = tid & 63;
    const int w = tid >> 6;
    const int wr = (w >> 1) * 64;
    const int wc = (w & 1) * 64;
    const int r0 = blockIdx.x * 128;

    {
        const uint4* U4 = (const uint4*)U;
        #pragma unroll
        for (int i = 0; i < 8; ++i) {
            int c = tid + 256 * i;
            int row = c >> 4, q = c & 15;
            uint4 v = (r0 + row < N) ? U4[(size_t)(r0 + row) * 16 + q]
                                     : make_uint4(0u, 0u, 0u, 0u);
            *(uint4*)&lA[swz_base(row, q)] = v;
        }
    }
    {
        const uint4* Wsrc = (const uint4*)WaT;
        #pragma unroll
        for (int i = 0; i < 8; ++i) {
            int c = tid + 256 * i;
            int row = c >> 4, q = c & 15;
            *(uint4*)&lW[swz_base(row, q)] = Wsrc[c];
        }
    }
    __syncthreads();

    const int am = lane & 15;
    const int kq = (lane >> 4) * 8;

    f32x4 acc[4][4];
    #pragma unroll
    for (int i = 0; i < 4; ++i)
        #pragma unroll
        for (int j = 0; j < 4; ++j) acc[i][j] = (f32x4){0.f, 0.f, 0.f, 0.f};

    #pragma unroll
    for (int ks = 0; ks < 4; ++ks) {
        int k0 = ks * 32 + kq;
        bf16x8 af[4], bq[4];
        #pragma unroll
        for (int i = 0; i < 4; ++i)
            af[i] = *(const bf16x8*)&lA[swz_base(wr + i * 16 + am, k0 >> 3)];
        #pragma unroll
        for (int j = 0; j < 4; ++j)
            bq[j] = *(const bf16x8*)&lW[swz_base(wc + j * 16 + am, k0 >> 3)];
        #pragma unroll
        for (int i = 0; i < 4; ++i)
            #pragma unroll
            for (int j = 0; j < 4; ++j)
                acc[i][j] = __builtin_amdgcn_mfma_f32_16x16x32_bf16(af[i], bq[j], acc[i][j], 0, 0, 0);
    }
    __syncthreads();

    #pragma unroll
    for (int j = 0; j < 4; ++j) {
        int col = wc + j * 16 + am;
        float bias = ba[col];
        #pragma unroll
        for (int i = 0; i < 4; ++i) {
            int rowb = wr + i * 16 + (lane >> 4) * 4;
            #pragma unroll
            for (int r = 0; r < 4; ++r) {
                float t = acc[i][j][r] + bias;
                t = t > 0.f ? t : 0.f;
                int row = rowb + r;
                lA[swz_base(row, col >> 3) + (col & 7)] = f2bf(t);
            }
        }
    }
    {
        const uint4* Wsrc = (const uint4*)WbT;
        #pragma unroll
        for (int i = 0; i < 8; ++i) {
            int c = tid + 256 * i;
            int row = c >> 4, q = c & 15;
            *(uint4*)&lW[swz_base(row, q)] = Wsrc[c];
        }
    }
    __syncthreads();

    #pragma unroll
    for (int i = 0; i < 4; ++i)
        #pragma unroll
        for (int j = 0; j < 4; ++j) acc[i][j] = (f32x4){0.f, 0.f, 0.f, 0.f};

    #pragma unroll
    for (int ks = 0; ks < 4; ++ks) {
        int k0 = ks * 32 + kq;
        bf16x8 af[4], bq[4];
        #pragma unroll
        for (int i = 0; i < 4; ++i)
            af[i] = *(const bf16x8*)&lA[swz_base(wr + i * 16 + am, k0 >> 3)];
        #pragma unroll
        for (int j = 0; j < 4; ++j)
            bq[j] = *(const bf16x8*)&lW[swz_base(wc + j * 16 + am, k0 >> 3)];
        #pragma unroll
        for (int i = 0; i < 4; ++i)
            #pragma unroll
            for (int j = 0; j < 4; ++j)
                acc[i][j] = __builtin_amdgcn_mfma_f32_16x16x32_bf16(af[i], bq[j], acc[i][j], 0, 0, 0);
    }

    if (!POOL) {
        #pragma unroll
        for (int j = 0; j < 4; ++j) {
            int col = wc + j * 16 + am;
            float bias = bb[col];
            #pragma unroll
            for (int i = 0; i < 4; ++i) {
                int rowb = wr + i * 16 + (lane >> 4) * 4;
                #pragma unroll
                for (int r = 0; r < 4; ++r) {
                    int row = r0 + rowb + r;
                    if (row < N) {
                        float t = acc[i][j][r] + bias;
                        t = t > 0.f ? t : 0.f;
                        Y[(size_t)row * 128 + col] = f2bf(t);
                    }
                }
            }
        }
    } else {
        __syncthreads();
        #pragma unroll
        for (int j = 0; j < 4; ++j) {
            int col = wc + j * 16 + am;
            float bias = bb[col];
            #pragma unroll
            for (int i = 0; i < 4; ++i) {
                int rowb = wr + i * 16 + (lane >> 4) * 4;
                #pragma unroll
                for (int r = 0; r < 4; ++r) {
                    float t = acc[i][j][r] + bias;
                    t = t > 0.f ? t : 0.f;
                    int row = rowb + r;
                    lA[swz_base(row, col >> 3) + (col & 7)] = f2bf(t);
                }
            }
        }
        if (tid < 128) bs[tid] = (r0 + tid < N) ? batch[r0 + tid] : -1;
        __syncthreads();
        const int col = tid & 127;
        const int half = tid >> 7;
        const int rbeg = half * 64, rend = rbeg + 64;
        float pacc = 0.f;
        int cur = bs[rbeg];
        for (int row = rbeg; row < rend; ++row) {
            int b = bs[row];
            if (b != cur) {
                if (cur >= 0) atomicAdd(&G[(size_t)cur * 128 + col], pacc);
                pacc = 0.f;
                cur = b;
            }
            unsigned short u = lA[swz_base(row, col >> 3) + (col & 7)];
            pacc += __uint_as_float((unsigned)u << 16);
        }
        if (cur >= 0) atomicAdd(&G[(size_t)cur * 128 + col], pacc);
    }
}

// ---------------- head ----------------
__global__ void k_head(const float* __restrict__ G,
                       const float* __restrict__ Wl1, const float* __restrict__ bl1,
                       const float* __restrict__ Wl2, const float* __restrict__ bl2,
                       int C, float* __restrict__ out) {
    __shared__ float sg[128];
    __shared__ float sh[128];
    __shared__ float sl[16];
    int row = blockIdx.x;
    int t = threadIdx.x;
    sg[t] = G[(size_t)row * 128 + t];
    __syncthreads();
    float a = bl1[t];
    for (int k = 0; k < 128; ++k) a += sg[k] * Wl1[k * 128 + t];
    sh[t] = a > 0.f ? a : 0.f;
    __syncthreads();
    if (t < C) {
        float l = bl2[t];
        for (int k = 0; k < 128; ++k) l += sh[k] * Wl2[k * C + t];
        sl[t] = l;
    }
    __syncthreads();
    if (t < C) {
        float m = -1e30f;
        for (int j = 0; j < C; ++j) m = fmaxf(m, sl[j]);
        float s = 0.f;
        for (int j = 0; j < C; ++j) s += __expf(sl[j] - m);
        out[(size_t)row * C + t] = sl[t] - m - __logf(s);
    }
}

extern "C" void kernel_launch(void* const* d_in, const int* in_sizes, int n_in,
                              void* d_out, int out_size, void* d_ws, size_t ws_size,
                              hipStream_t stream) {
    const float* x    = (const float*)d_in[0];
    const int*   ei   = (const int*)d_in[1];     // [2][E]
    const int*   batch= (const int*)d_in[2];
    const float* W1a  = (const float*)d_in[3];
    const float* b1a  = (const float*)d_in[4];
    const float* W1b  = (const float*)d_in[5];
    const float* b1b  = (const float*)d_in[6];
    const float* W2a  = (const float*)d_in[7];
    const float* b2a  = (const float*)d_in[8];
    const float* W2b  = (const float*)d_in[9];
    const float* b2b  = (const float*)d_in[10];
    const float* Wl1  = (const float*)d_in[11];
    const float* bl1  = (const float*)d_in[12];
    const float* Wl2  = (const float*)d_in[13];
    const float* bl2  = (const float*)d_in[14];
    float* out = (float*)d_out;

    const int N = in_sizes[2];
    const int E = in_sizes[1] / 2;
    const int C = in_sizes[13] / 128;

    const int nbuck = (N >> 7) + 1;
    const int epb = (E + SBLK - 1) / SBLK;

    char* p = (char*)d_ws;
    auto alloc = [&](size_t bytes) {
        char* r = p;
        p += (bytes + 255) & ~(size_t)255;
        return r;
    };
    unsigned* xb   = (unsigned*)alloc((size_t)N * 64 * 4);     // x bf16, row-major
    unsigned* hA   = (unsigned*)alloc((size_t)N * 64 * 4);     // agg out (bf16)
    unsigned* hB   = (unsigned*)alloc((size_t)N * 64 * 4);     // conv1 out (bf16)
    float* g       = (float*)alloc((size_t)NUM_GRAPHS * 128 * 4);
    int* rp        = (int*)alloc((size_t)(N + 1) * 4);
    int* srcs      = (int*)alloc((size_t)E * 4);
    unsigned* ebuf = (unsigned*)alloc((size_t)nbuck * CAP * 4);
    int* gcur      = (int*)alloc((size_t)1024 * 4);
    unsigned short* wt = (unsigned short*)alloc((size_t)4 * 16384 * 2);
    (void)ws_size; (void)n_in; (void)out_size;

    hipMemsetAsync(gcur, 0, (size_t)nbuck * 4, stream);

    // CSR: fused hist+reserve+scatter (+ x->bf16, zero G, weight prep), then fine sort
    k_sort<<<SBLK + 2048 + 64 + 256, 256, 0, stream>>>(
        ei, ei + E, E, epb, nbuck, gcur, ebuf, x, N, xb, g,
        W1a, W1b, W2a, W2b, wt);
    k_bucket<<<nbuck, 256, 0, stream>>>(ebuf, gcur, nbuck, N, rp, srcs);

    const int mb = (N + 127) / 128;
    const int qw = (N + 3) / 4;
    const int qb = (qw + 3) / 4;

    // conv1
    k_aggq<<<qb, 256, 0, stream>>>((const uint4*)xb, rp, srcs, N, (uint4*)hA);
    k_mlp<false><<<mb, 256, 0, stream>>>((const unsigned short*)hA, N, wt, b1a,
                                         wt + 16384, b1b, (unsigned short*)hB,
                                         nullptr, nullptr);
    // conv2 (+ fused global_add_pool)
    k_aggq<<<qb, 256, 0, stream>>>((const uint4*)hB, rp, srcs, N, (uint4*)hA);
    k_mlp<true><<<mb, 256, 0, stream>>>((const unsigned short*)hA, N, wt + 2 * 16384, b2a,
                                        wt + 3 * 16384, b2b, nullptr,
                                        batch, g);
    // head
    k_head<<<NUM_GRAPHS, 128, 0, stream>>>(g, Wl1, bl1, Wl2, bl2, C, out);
}

// Round 9
// 354.814 us; speedup vs baseline: 1.2240x; 1.0372x over previous
//
#include <hip/hip_runtime.h>
#include <hip/hip_bf16.h>
#include <math.h>

#define NUM_GRAPHS 1024
#define SBLK 256          // sort blocks in fused CSR kernel
#define CAP 4096          // per-bucket ebuf capacity (mean 2046, 45 sigma)

typedef __attribute__((ext_vector_type(8))) short bf16x8;
typedef __attribute__((ext_vector_type(4))) float f32x4;

static __device__ __forceinline__ unsigned short f2bf(float f) {
    union { float f; unsigned u; } v; v.f = f;
    unsigned r = v.u + 0x7fffu + ((v.u >> 16) & 1u);   // round-to-nearest-even
    return (unsigned short)(r >> 16);
}
static __device__ __forceinline__ float bf_lo(unsigned u) { return __uint_as_float(u << 16); }
static __device__ __forceinline__ float bf_hi(unsigned u) { return __uint_as_float(u & 0xffff0000u); }

// exclusive scan of min(tot[i],CAP) into LDS bb[0..nbuck]; 256 threads, nbuck<=1024
static __device__ void scan_tot(const int* __restrict__ tot, int nbuck,
                                int* bb, int* tmp) {
    const int t = threadIdx.x;
    int v[4];
    int lsum = 0;
    #pragma unroll
    for (int j = 0; j < 4; ++j) {
        int idx = 4 * t + j;
        v[j] = (idx < nbuck) ? min(tot[idx], CAP) : 0;
        lsum += v[j];
    }
    tmp[t] = lsum;
    __syncthreads();
    for (int off = 1; off < 256; off <<= 1) {
        int a = (t >= off) ? tmp[t - off] : 0;
        __syncthreads();
        tmp[t] += a;
        __syncthreads();
    }
    int run = tmp[t] - lsum;
    #pragma unroll
    for (int j = 0; j < 4; ++j) {
        int idx = 4 * t + j;
        if (idx < nbuck) bb[idx] = run;
        run += v[j];
    }
    if (t == 255) bb[nbuck] = tmp[255];
    __syncthreads();
}

// ---------------- fused CSR pass 1: hist + chunk-reserve + scatter ----------------
// Also: x->bf16 (row-major), zero G, weight prep — as extra block ranges.
// gcur[] must be zeroed before this kernel (hipMemsetAsync).
__global__ void k_sort(const int* __restrict__ eiSrc, const int* __restrict__ eiDst,
                       int E, int epb, int nbuck,
                       int* __restrict__ gcur, unsigned* __restrict__ ebuf,
                       const float* __restrict__ x, int N, unsigned* __restrict__ xb,
                       float* __restrict__ G,
                       const float* __restrict__ W0, const float* __restrict__ W1,
                       const float* __restrict__ W2, const float* __restrict__ W3,
                       unsigned short* __restrict__ wt) {
    if ((int)blockIdx.x < SBLK) {
        __shared__ int hist[1024];
        __shared__ int cur[1024];
        const int t = threadIdx.x;
        for (int i = t; i < 1024; i += 256) hist[i] = 0;
        __syncthreads();
        const int e0 = blockIdx.x * epb;
        const int e1 = min(E, e0 + epb);
        for (int e = e0 + t; e < e1; e += 256) atomicAdd(&hist[eiDst[e] >> 7], 1);
        __syncthreads();
        for (int b = t; b < nbuck; b += 256) {
            int c = hist[b];
            cur[b] = b * CAP + (c > 0 ? atomicAdd(&gcur[b], c) : 0);
        }
        __syncthreads();
        for (int e = e0 + t; e < e1; e += 256) {
            int d = eiDst[e];
            int s = eiSrc[e];
            int b = d >> 7;
            int pos = atomicAdd(&cur[b], 1);
            if (pos < (b + 1) * CAP)   // overflow guard (45-sigma event)
                ebuf[pos] = (unsigned)s | ((unsigned)(d & 127) << 25);
        }
    } else if ((int)blockIdx.x < SBLK + 2048) {
        const int n4 = N * 32;
        int i = (blockIdx.x - SBLK) * 256 + threadIdx.x;
        const int stride = 2048 * 256;
        const float4* x4 = (const float4*)x;
        for (; i < n4; i += stride) {
            float4 v = x4[i];
            unsigned lo = (unsigned)f2bf(v.x) | ((unsigned)f2bf(v.y) << 16);
            unsigned hi = (unsigned)f2bf(v.z) | ((unsigned)f2bf(v.w) << 16);
            ((uint2*)xb)[i] = make_uint2(lo, hi);
        }
    } else if ((int)blockIdx.x < SBLK + 2048 + 64) {
        int i = (blockIdx.x - SBLK - 2048) * 256 + threadIdx.x;
        float4* G4 = (float4*)G;
        for (; i < NUM_GRAPHS * 32; i += 64 * 256)
            G4[i] = make_float4(0.f, 0.f, 0.f, 0.f);
    } else {
        int lb = blockIdx.x - SBLK - 2048 - 64;     // 0..255
        int b4 = lb >> 6;                           // 0..3
        const float* W = (b4 == 0) ? W0 : (b4 == 1) ? W1 : (b4 == 2) ? W2 : W3;
        int idx = (lb & 63) * 256 + threadIdx.x;    // 0..16383
        int k = idx >> 7, n = idx & 127;
        wt[b4 * 16384 + n * 128 + k] = f2bf(W[idx]);
    }
}

// ---------------- fused CSR pass 2 + conv1 gather ----------------
// One block per bucket: fine-sort ~2600 edges in LDS -> write rp/srcs to global
// (for conv2) -> gather this bucket's 128 nodes using LDS-resident srcs.
__global__ __launch_bounds__(256, 6)
void k_bktagg(const unsigned* __restrict__ ebuf, const int* __restrict__ gcur,
              int nbuck, int N, int* __restrict__ rp, int* __restrict__ srcs,
              const uint4* __restrict__ H4, uint4* __restrict__ out) {
    __shared__ int bb[1025];
    __shared__ int tmp[256];
    __shared__ int h[128];
    __shared__ int cur[128];
    __shared__ int lrp[129];
    __shared__ int lsrcs[CAP];
    const int t = threadIdx.x;
    const int b = blockIdx.x;
    scan_tot(gcur, nbuck, bb, tmp);
    const int base = bb[b];
    const int cntb = bb[b + 1] - base;
    const unsigned* eb = ebuf + (size_t)b * CAP;
    if (t < 128) h[t] = 0;
    __syncthreads();
    for (int i = t; i < cntb; i += 256) atomicAdd(&h[eb[i] >> 25], 1);
    __syncthreads();
    int c0 = (t < 128) ? h[t] : 0;
    for (int off = 1; off < 128; off <<= 1) {
        int a = (t >= off && t < 128) ? h[t - off] : 0;
        __syncthreads();
        if (t < 128) h[t] += a;
        __syncthreads();
    }
    if (t < 128) {
        int excl = h[t] - c0;
        cur[t] = excl;
        lrp[t] = excl;
        if (t == 127) lrp[128] = h[127];
        int d = (b << 7) + t;
        if (d < N) rp[d] = base + excl;
        if (d == N) rp[N] = base + excl;
    }
    __syncthreads();
    for (int i = t; i < cntb; i += 256) {
        unsigned pck = eb[i];
        int pos = atomicAdd(&cur[pck >> 25], 1);
        int sv = (int)(pck & 0x01FFFFFFu);
        lsrcs[pos] = sv;
        srcs[base + pos] = sv;
    }
    __syncthreads();

    // ---- gather: 16 quarter-waves x 8 nodes each; lane holds uint4 = 8 feats ----
    const int lane = t & 63;
    const int w = t >> 6;
    const int q = lane >> 4, ql = lane & 15;
    const int qid = w * 4 + q;                  // 0..15
    for (int nn = 0; nn < 8; ++nn) {
        const int loc = qid * 8 + nn;           // 0..127
        const int n = (b << 7) + loc;
        if (n >= N) break;
        uint4 s0 = H4[(size_t)n * 16 + ql];
        float a[8];
        a[0] = bf_lo(s0.x); a[1] = bf_hi(s0.x);
        a[2] = bf_lo(s0.y); a[3] = bf_hi(s0.y);
        a[4] = bf_lo(s0.z); a[5] = bf_hi(s0.z);
        a[6] = bf_lo(s0.w); a[7] = bf_hi(s0.w);
        int j = lrp[loc], e = lrp[loc + 1];
        while (j + 4 <= e) {
            int i0 = lsrcs[j], i1 = lsrcs[j + 1], i2 = lsrcs[j + 2], i3 = lsrcs[j + 3];
            uint4 v0 = H4[(size_t)i0 * 16 + ql];
            uint4 v1 = H4[(size_t)i1 * 16 + ql];
            uint4 v2 = H4[(size_t)i2 * 16 + ql];
            uint4 v3 = H4[(size_t)i3 * 16 + ql];
            a[0] += bf_lo(v0.x) + bf_lo(v1.x) + bf_lo(v2.x) + bf_lo(v3.x);
            a[1] += bf_hi(v0.x) + bf_hi(v1.x) + bf_hi(v2.x) + bf_hi(v3.x);
            a[2] += bf_lo(v0.y) + bf_lo(v1.y) + bf_lo(v2.y) + bf_lo(v3.y);
            a[3] += bf_hi(v0.y) + bf_hi(v1.y) + bf_hi(v2.y) + bf_hi(v3.y);
            a[4] += bf_lo(v0.z) + bf_lo(v1.z) + bf_lo(v2.z) + bf_lo(v3.z);
            a[5] += bf_hi(v0.z) + bf_hi(v1.z) + bf_hi(v2.z) + bf_hi(v3.z);
            a[6] += bf_lo(v0.w) + bf_lo(v1.w) + bf_lo(v2.w) + bf_lo(v3.w);
            a[7] += bf_hi(v0.w) + bf_hi(v1.w) + bf_hi(v2.w) + bf_hi(v3.w);
            j += 4;
        }
        while (j < e) {
            uint4 v = H4[(size_t)lsrcs[j] * 16 + ql];
            a[0] += bf_lo(v.x); a[1] += bf_hi(v.x);
            a[2] += bf_lo(v.y); a[3] += bf_hi(v.y);
            a[4] += bf_lo(v.z); a[5] += bf_hi(v.z);
            a[6] += bf_lo(v.w); a[7] += bf_hi(v.w);
            ++j;
        }
        uint4 o;
        o.x = (unsigned)f2bf(a[0]) | ((unsigned)f2bf(a[1]) << 16);
        o.y = (unsigned)f2bf(a[2]) | ((unsigned)f2bf(a[3]) << 16);
        o.z = (unsigned)f2bf(a[4]) | ((unsigned)f2bf(a[5]) << 16);
        o.w = (unsigned)f2bf(a[6]) | ((unsigned)f2bf(a[7]) << 16);
        out[(size_t)n * 16 + ql] = o;
    }
}

// ---------------- quarter-wave aggregation (conv2) ----------------
__device__ __forceinline__ void acc8(float* a, uint4 v) {
    a[0] += bf_lo(v.x); a[1] += bf_hi(v.x);
    a[2] += bf_lo(v.y); a[3] += bf_hi(v.y);
    a[4] += bf_lo(v.z); a[5] += bf_hi(v.z);
    a[6] += bf_lo(v.w); a[7] += bf_hi(v.w);
}

__global__ __launch_bounds__(256, 8)
void k_aggq(const uint4* __restrict__ H4, const int* __restrict__ rp,
            const int* __restrict__ srcs, int N, uint4* __restrict__ out) {
    int gw = (blockIdx.x * blockDim.x + threadIdx.x) >> 6;
    int lane = threadIdx.x & 63;
    int q = lane >> 4, ql = lane & 15;
    int n = gw * 4 + q;
    if (gw * 4 >= N) return;
    bool act = (n < N);
    int nc = act ? n : 0;
    uint4 s0 = H4[(size_t)nc * 16 + ql];
    float a[8];
    a[0] = bf_lo(s0.x); a[1] = bf_hi(s0.x);
    a[2] = bf_lo(s0.y); a[3] = bf_hi(s0.y);
    a[4] = bf_lo(s0.z); a[5] = bf_hi(s0.z);
    a[6] = bf_lo(s0.w); a[7] = bf_hi(s0.w);
    int j = act ? rp[nc] : 0;
    int e = act ? rp[nc + 1] : 0;
    while (j + 4 <= e) {
        int i0 = srcs[j], i1 = srcs[j + 1], i2 = srcs[j + 2], i3 = srcs[j + 3];
        uint4 v0 = H4[(size_t)i0 * 16 + ql];
        uint4 v1 = H4[(size_t)i1 * 16 + ql];
        uint4 v2 = H4[(size_t)i2 * 16 + ql];
        uint4 v3 = H4[(size_t)i3 * 16 + ql];
        acc8(a, v0); acc8(a, v1); acc8(a, v2); acc8(a, v3);
        j += 4;
    }
    while (j < e) {
        uint4 v = H4[(size_t)srcs[j] * 16 + ql];
        acc8(a, v);
        ++j;
    }
    if (act) {
        uint4 o;
        o.x = (unsigned)f2bf(a[0]) | ((unsigned)f2bf(a[1]) << 16);
        o.y = (unsigned)f2bf(a[2]) | ((unsigned)f2bf(a[3]) << 16);
        o.z = (unsigned)f2bf(a[4]) | ((unsigned)f2bf(a[5]) << 16);
        o.w = (unsigned)f2bf(a[6]) | ((unsigned)f2bf(a[7]) << 16);
        out[(size_t)n * 16 + ql] = o;
    }
}

// ---------------- fused 2-layer MLP; POOL variant pools into G ----------------
__device__ __forceinline__ int swz_base(int row, int chunk) {
    return row * 128 + ((chunk ^ (row & 7)) << 3);
}

template <bool POOL>
__global__ __launch_bounds__(256, 2)
void k_mlp(const unsigned short* __restrict__ U, int N,
           const unsigned short* __restrict__ WaT, const float* __restrict__ ba,
           const unsigned short* __restrict__ WbT, const float* __restrict__ bb,
           unsigned short* __restrict__ Y,
           const int* __restrict__ batch, float* __restrict__ G) {
    __shared__ unsigned short lA[128 * 128];
    __shared__ unsigned short lW[128 * 128];
    __shared__ int bs[128];

    const int tid = threadIdx.x;
    const int lane = tid & 63;
    const int w = tid >> 6;
    const int wr = (w >> 1) * 64;
    const int wc = (w & 1) * 64;
    const int r0 = blockIdx.x * 128;

    {
        const uint4* U4 = (const uint4*)U;
        #pragma unroll
        for (int i = 0; i < 8; ++i) {
            int c = tid + 256 * i;
            int row = c >> 4, q = c & 15;
            uint4 v = (r0 + row < N) ? U4[(size_t)(r0 + row) * 16 + q]
                                     : make_uint4(0u, 0u, 0u, 0u);
            *(uint4*)&lA[swz_base(row, q)] = v;
        }
    }
    {
        const uint4* Wsrc = (const uint4*)WaT;
        #pragma unroll
        for (int i = 0; i < 8; ++i) {
            int c = tid + 256 * i;
            int row = c >> 4, q = c & 15;
            *(uint4*)&lW[swz_base(row, q)] = Wsrc[c];
        }
    }
    __syncthreads();

    const int am = lane & 15;
    const int kq = (lane >> 4) * 8;

    f32x4 acc[4][4];
    #pragma unroll
    for (int i = 0; i < 4; ++i)
        #pragma unroll
        for (int j = 0; j < 4; ++j) acc[i][j] = (f32x4){0.f, 0.f, 0.f, 0.f};

    #pragma unroll
    for (int ks = 0; ks < 4; ++ks) {
        int k0 = ks * 32 + kq;
        bf16x8 af[4], bq[4];
        #pragma unroll
        for (int i = 0; i < 4; ++i)
            af[i] = *(const bf16x8*)&lA[swz_base(wr + i * 16 + am, k0 >> 3)];
        #pragma unroll
        for (int j = 0; j < 4; ++j)
            bq[j] = *(const bf16x8*)&lW[swz_base(wc + j * 16 + am, k0 >> 3)];
        #pragma unroll
        for (int i = 0; i < 4; ++i)
            #pragma unroll
            for (int j = 0; j < 4; ++j)
                acc[i][j] = __builtin_amdgcn_mfma_f32_16x16x32_bf16(af[i], bq[j], acc[i][j], 0, 0, 0);
    }
    __syncthreads();

    #pragma unroll
    for (int j = 0; j < 4; ++j) {
        int col = wc + j * 16 + am;
        float bias = ba[col];
        #pragma unroll
        for (int i = 0; i < 4; ++i) {
            int rowb = wr + i * 16 + (lane >> 4) * 4;
            #pragma unroll
            for (int r = 0; r < 4; ++r) {
                float t = acc[i][j][r] + bias;
                t = t > 0.f ? t : 0.f;
                int row = rowb + r;
                lA[swz_base(row, col >> 3) + (col & 7)] = f2bf(t);
            }
        }
    }
    {
        const uint4* Wsrc = (const uint4*)WbT;
        #pragma unroll
        for (int i = 0; i < 8; ++i) {
            int c = tid + 256 * i;
            int row = c >> 4, q = c & 15;
            *(uint4*)&lW[swz_base(row, q)] = Wsrc[c];
        }
    }
    __syncthreads();

    #pragma unroll
    for (int i = 0; i < 4; ++i)
        #pragma unroll
        for (int j = 0; j < 4; ++j) acc[i][j] = (f32x4){0.f, 0.f, 0.f, 0.f};

    #pragma unroll
    for (int ks = 0; ks < 4; ++ks) {
        int k0 = ks * 32 + kq;
        bf16x8 af[4], bq[4];
        #pragma unroll
        for (int i = 0; i < 4; ++i)
            af[i] = *(const bf16x8*)&lA[swz_base(wr + i * 16 + am, k0 >> 3)];
        #pragma unroll
        for (int j = 0; j < 4; ++j)
            bq[j] = *(const bf16x8*)&lW[swz_base(wc + j * 16 + am, k0 >> 3)];
        #pragma unroll
        for (int i = 0; i < 4; ++i)
            #pragma unroll
            for (int j = 0; j < 4; ++j)
                acc[i][j] = __builtin_amdgcn_mfma_f32_16x16x32_bf16(af[i], bq[j], acc[i][j], 0, 0, 0);
    }

    if (!POOL) {
        #pragma unroll
        for (int j = 0; j < 4; ++j) {
            int col = wc + j * 16 + am;
            float bias = bb[col];
            #pragma unroll
            for (int i = 0; i < 4; ++i) {
                int rowb = wr + i * 16 + (lane >> 4) * 4;
                #pragma unroll
                for (int r = 0; r < 4; ++r) {
                    int row = r0 + rowb + r;
                    if (row < N) {
                        float t = acc[i][j][r] + bias;
                        t = t > 0.f ? t : 0.f;
                        Y[(size_t)row * 128 + col] = f2bf(t);
                    }
                }
            }
        }
    } else {
        __syncthreads();
        #pragma unroll
        for (int j = 0; j < 4; ++j) {
            int col = wc + j * 16 + am;
            float bias = bb[col];
            #pragma unroll
            for (int i = 0; i < 4; ++i) {
                int rowb = wr + i * 16 + (lane >> 4) * 4;
                #pragma unroll
                for (int r = 0; r < 4; ++r) {
                    float t = acc[i][j][r] + bias;
                    t = t > 0.f ? t : 0.f;
                    int row = rowb + r;
                    lA[swz_base(row, col >> 3) + (col & 7)] = f2bf(t);
                }
            }
        }
        if (tid < 128) bs[tid] = (r0 + tid < N) ? batch[r0 + tid] : -1;
        __syncthreads();
        const int col = tid & 127;
        const int half = tid >> 7;
        const int rbeg = half * 64, rend = rbeg + 64;
        float pacc = 0.f;
        int cur = bs[rbeg];
        for (int row = rbeg; row < rend; ++row) {
            int b = bs[row];
            if (b != cur) {
                if (cur >= 0) atomicAdd(&G[(size_t)cur * 128 + col], pacc);
                pacc = 0.f;
                cur = b;
            }
            unsigned short u = lA[swz_base(row, col >> 3) + (col & 7)];
            pacc += __uint_as_float((unsigned)u << 16);
        }
        if (cur >= 0) atomicAdd(&G[(size_t)cur * 128 + col], pacc);
    }
}

// ---------------- head ----------------
__global__ void k_head(const float* __restrict__ G,
                       const float* __restrict__ Wl1, const float* __restrict__ bl1,
                       const float* __restrict__ Wl2, const float* __restrict__ bl2,
                       int C, float* __restrict__ out) {
    __shared__ float sg[128];
    __shared__ float sh[128];
    __shared__ float sl[16];
    int row = blockIdx.x;
    int t = threadIdx.x;
    sg[t] = G[(size_t)row * 128 + t];
    __syncthreads();
    float a = bl1[t];
    for (int k = 0; k < 128; ++k) a += sg[k] * Wl1[k * 128 + t];
    sh[t] = a > 0.f ? a : 0.f;
    __syncthreads();
    if (t < C) {
        float l = bl2[t];
        for (int k = 0; k < 128; ++k) l += sh[k] * Wl2[k * C + t];
        sl[t] = l;
    }
    __syncthreads();
    if (t < C) {
        float m = -1e30f;
        for (int j = 0; j < C; ++j) m = fmaxf(m, sl[j]);
        float s = 0.f;
        for (int j = 0; j < C; ++j) s += __expf(sl[j] - m);
        out[(size_t)row * C + t] = sl[t] - m - __logf(s);
    }
}

extern "C" void kernel_launch(void* const* d_in, const int* in_sizes, int n_in,
                              void* d_out, int out_size, void* d_ws, size_t ws_size,
                              hipStream_t stream) {
    const float* x    = (const float*)d_in[0];
    const int*   ei   = (const int*)d_in[1];     // [2][E]
    const int*   batch= (const int*)d_in[2];
    const float* W1a  = (const float*)d_in[3];
    const float* b1a  = (const float*)d_in[4];
    const float* W1b  = (const float*)d_in[5];
    const float* b1b  = (const float*)d_in[6];
    const float* W2a  = (const float*)d_in[7];
    const float* b2a  = (const float*)d_in[8];
    const float* W2b  = (const float*)d_in[9];
    const float* b2b  = (const float*)d_in[10];
    const float* Wl1  = (const float*)d_in[11];
    const float* bl1  = (const float*)d_in[12];
    const float* Wl2  = (const float*)d_in[13];
    const float* bl2  = (const float*)d_in[14];
    float* out = (float*)d_out;

    const int N = in_sizes[2];
    const int E = in_sizes[1] / 2;
    const int C = in_sizes[13] / 128;

    const int nbuck = (N >> 7) + 1;
    const int epb = (E + SBLK - 1) / SBLK;

    char* p = (char*)d_ws;
    auto alloc = [&](size_t bytes) {
        char* r = p;
        p += (bytes + 255) & ~(size_t)255;
        return r;
    };
    unsigned* xb   = (unsigned*)alloc((size_t)N * 64 * 4);     // x bf16, row-major
    unsigned* hA   = (unsigned*)alloc((size_t)N * 64 * 4);     // agg out (bf16)
    unsigned* hB   = (unsigned*)alloc((size_t)N * 64 * 4);     // conv1 out (bf16)
    float* g       = (float*)alloc((size_t)NUM_GRAPHS * 128 * 4);
    int* rp        = (int*)alloc((size_t)(N + 1) * 4);
    int* srcs      = (int*)alloc((size_t)E * 4);
    unsigned* ebuf = (unsigned*)alloc((size_t)nbuck * CAP * 4);
    int* gcur      = (int*)alloc((size_t)1024 * 4);
    unsigned short* wt = (unsigned short*)alloc((size_t)4 * 16384 * 2);
    (void)ws_size; (void)n_in; (void)out_size;

    hipMemsetAsync(gcur, 0, (size_t)nbuck * 4, stream);

    // CSR pass 1 (+ x->bf16, zero G, weight prep)
    k_sort<<<SBLK + 2048 + 64 + 256, 256, 0, stream>>>(
        ei, ei + E, E, epb, nbuck, gcur, ebuf, x, N, xb, g,
        W1a, W1b, W2a, W2b, wt);

    const int mb = (N + 127) / 128;
    const int qw = (N + 3) / 4;
    const int qb = (qw + 3) / 4;

    // CSR pass 2 + conv1 gather (fused)
    k_bktagg<<<nbuck, 256, 0, stream>>>(ebuf, gcur, nbuck, N, rp, srcs,
                                        (const uint4*)xb, (uint4*)hA);
    k_mlp<false><<<mb, 256, 0, stream>>>((const unsigned short*)hA, N, wt, b1a,
                                         wt + 16384, b1b, (unsigned short*)hB,
                                         nullptr, nullptr);
    // conv2 (+ fused global_add_pool)
    k_aggq<<<qb, 256, 0, stream>>>((const uint4*)hB, rp, srcs, N, (uint4*)hA);
    k_mlp<true><<<mb, 256, 0, stream>>>((const unsigned short*)hA, N, wt + 2 * 16384, b2a,
                                        wt + 3 * 16384, b2b, nullptr,
                                        batch, g);
    // head
    k_head<<<NUM_GRAPHS, 128, 0, stream>>>(g, Wl1, bl1, Wl2, bl2, C, out);
}